// Round 5
// baseline (458.802 us; speedup 1.0000x reference)
//
#include <hip/hip_runtime.h>
#include <hip/hip_bf16.h>
#include <math.h>

#define IN_DIM 512
#define NHEAD 4
#define CDIM 64
#define HC 256           // NHEAD*CDIM
#define NEG_SLOPE 0.2f
#define GBM 128          // GEMM rows per block

typedef __attribute__((ext_vector_type(8))) short bf16x8;
typedef __attribute__((ext_vector_type(4))) float f32x4;

__device__ __forceinline__ unsigned short f2bf_rne(float f) {
    unsigned int u = __float_as_uint(f);
    u = u + 0x7fffu + ((u >> 16) & 1u);
    return (unsigned short)(u >> 16);
}
__device__ __forceinline__ float bf2f(unsigned short h) {
    return __uint_as_float(((unsigned int)h) << 16);
}
__device__ __forceinline__ float leaky_exp(float t) {
    t = (t >= 0.f) ? t : NEG_SLOPE * t;
    return __expf(t);
}

// ---- W prep: split fp32 W[512][256] into bf16 hi/lo panels, transposed +
// bank-swizzle pre-permuted so the GEMM stages B with linear global_load_lds.
// Panel layout: Wp[kstep][col][slot][8 k-elems], slot = kg ^ ((col>>1)&3).
__global__ __launch_bounds__(256) void prep_w_kernel(
    const float* __restrict__ W,
    unsigned short* __restrict__ Wp_hi,
    unsigned short* __restrict__ Wp_lo)
{
    int idx = blockIdx.x * 256 + threadIdx.x;   // 16 ksteps * 256 cols * 4 slots
    int slot  = idx & 3;
    int col   = (idx >> 2) & 255;
    int kstep = idx >> 10;
    int kg    = slot ^ ((col >> 1) & 3);
    int kbase = kstep * 32 + kg * 8;
    bf16x8 vh, vl;
#pragma unroll
    for (int e = 0; e < 8; ++e) {
        float f = W[(size_t)(kbase + e) * HC + col];
        unsigned short h = f2bf_rne(f);
        vh[e] = (short)h;
        vl[e] = (short)f2bf_rne(f - bf2f(h));
    }
    size_t off = (size_t)idx * 8;
    *(bf16x8*)(Wp_hi + off) = vh;
    *(bf16x8*)(Wp_lo + off) = vl;
}

// ---- GEMM h = x@W via bf16 split MFMA, pipelined (B double-buffered,
// A reg-prefetch), fused attention-coef epilogue. 512 thr = 8 waves
// (2 row x 4 col groups); col group == head.
__global__ __launch_bounds__(512) void gemm_coef_kernel(
    const float* __restrict__ x,
    const unsigned short* __restrict__ Wp_hi,
    const unsigned short* __restrict__ Wp_lo,
    const float* __restrict__ att_src,
    const float* __restrict__ att_dst,
    float* __restrict__ Hbuf,
    float* __restrict__ a_src,
    float* __restrict__ a_dst,
    int M)
{
    __shared__ char smem[81920];
    char* As_hi = smem;                 // 128 rows * 64B = 8KB
    char* As_lo = smem + 8192;          // 8KB
    // B double buffer at smem+16384: buf b = +b*32768 (hi 16KB, lo 16KB)

    const int tid  = threadIdx.x;
    const int lane = tid & 63;
    const int wv   = tid >> 6;         // 0..7
    const int head = wv & 3;
    const int wrow = (wv >> 2) * 64;
    const int brow = blockIdx.x * GBM;
    const int r16  = lane & 15;
    const int kgrp = lane >> 4;

    const int  ar      = tid >> 2;     // 0..127 (row within tile)
    const int  aslot   = tid & 3;      // 16B slot within row
    const bool arow_ok = (brow + ar) < M;
    const float* aptr  = x + (size_t)(brow + ar) * IN_DIM + aslot * 8;
    const int  a_addr  = ar * 64 + ((aslot ^ ((ar >> 1) & 3)) << 4);

    f32x4 acc[4][4];
#pragma unroll
    for (int i = 0; i < 4; ++i)
#pragma unroll
        for (int j = 0; j < 4; ++j) acc[i][j] = (f32x4)(0.f);

    auto stageB = [&](int ks, int buf) {
        const char* gh = (const char*)Wp_hi + (size_t)ks * 16384 + wv * 2048 + (lane << 4);
        const char* gl = (const char*)Wp_lo + (size_t)ks * 16384 + wv * 2048 + (lane << 4);
        char* lh = smem + 16384 + buf * 32768 + wv * 2048;
        char* ll = lh + 16384;
#pragma unroll
        for (int i = 0; i < 2; ++i) {
            __builtin_amdgcn_global_load_lds(
                (const __attribute__((address_space(1))) unsigned int*)(gh + i * 1024),
                (__attribute__((address_space(3))) unsigned int*)(lh + i * 1024), 16, 0, 0);
            __builtin_amdgcn_global_load_lds(
                (const __attribute__((address_space(1))) unsigned int*)(gl + i * 1024),
                (__attribute__((address_space(3))) unsigned int*)(ll + i * 1024), 16, 0, 0);
        }
    };
    auto loadA = [&](int ks, float4& v0, float4& v1) {
        v0 = make_float4(0.f, 0.f, 0.f, 0.f);
        v1 = v0;
        if (arow_ok) {
            const float* p = aptr + ks * 32;
            v0 = *(const float4*)p;
            v1 = *(const float4*)(p + 4);
        }
    };
    auto writeA = [&](const float4& v0, const float4& v1) {
        float fv[8] = {v0.x, v0.y, v0.z, v0.w, v1.x, v1.y, v1.z, v1.w};
        bf16x8 vh, vl;
#pragma unroll
        for (int e = 0; e < 8; ++e) {
            unsigned short hh = f2bf_rne(fv[e]);
            vh[e] = (short)hh;
            vl[e] = (short)f2bf_rne(fv[e] - bf2f(hh));
        }
        *(bf16x8*)(As_hi + a_addr) = vh;
        *(bf16x8*)(As_lo + a_addr) = vl;
    };

    // prologue
    {
        float4 pv0, pv1;
        stageB(0, 0);
        loadA(0, pv0, pv1);
        writeA(pv0, pv1);
        __syncthreads();   // drains vmcnt (B0 in LDS) + lgkm (A0 in LDS)
    }

    for (int ks = 0; ks < 16; ++ks) {
        const int cb = ks & 1;
        float4 nv0, nv1;
        if (ks < 15) {
            stageB(ks + 1, cb ^ 1);   // async into other B buffer
            loadA(ks + 1, nv0, nv1);  // A prefetch to regs
        }

        bf16x8 ah[4], al[4], bh[4], bl[4];
        char* BsH = smem + 16384 + cb * 32768;
        char* BsL = BsH + 16384;
#pragma unroll
        for (int fr = 0; fr < 4; ++fr) {
            int row = wrow + fr * 16 + r16;
            int addr = row * 64 + ((kgrp ^ ((row >> 1) & 3)) << 4);
            ah[fr] = *(bf16x8*)(As_hi + addr);
            al[fr] = *(bf16x8*)(As_lo + addr);
        }
#pragma unroll
        for (int fc = 0; fc < 4; ++fc) {
            int col = head * 64 + fc * 16 + r16;
            int addr = col * 64 + ((kgrp ^ ((col >> 1) & 3)) << 4);
            bh[fc] = *(bf16x8*)(BsH + addr);
            bl[fc] = *(bf16x8*)(BsL + addr);
        }
#pragma unroll
        for (int fr = 0; fr < 4; ++fr)
#pragma unroll
            for (int fc = 0; fc < 4; ++fc) {
                acc[fr][fc] = __builtin_amdgcn_mfma_f32_16x16x32_bf16(ah[fr], bh[fc], acc[fr][fc], 0, 0, 0);
                acc[fr][fc] = __builtin_amdgcn_mfma_f32_16x16x32_bf16(ah[fr], bl[fc], acc[fr][fc], 0, 0, 0);
                acc[fr][fc] = __builtin_amdgcn_mfma_f32_16x16x32_bf16(al[fr], bh[fc], acc[fr][fc], 0, 0, 0);
            }

        if (ks < 15) {
            __syncthreads();     // all ds_reads of As done -> safe to overwrite
            writeA(nv0, nv1);
            __syncthreads();     // As(next) visible; drains vmcnt -> Bs(next) ready
        }
    }

    // epilogue: store Hbuf + fused a_src/a_dst (wave col-group == head)
    float asv[4], adv[4];
#pragma unroll
    for (int fc = 0; fc < 4; ++fc) {
        int col = head * 64 + fc * 16 + r16;
        asv[fc] = att_src[col];
        adv[fc] = att_dst[col];
    }
#pragma unroll
    for (int fr = 0; fr < 4; ++fr) {
#pragma unroll
        for (int q = 0; q < 4; ++q) {
            int row = brow + wrow + fr * 16 + kgrp * 4 + q;
            bool ok = row < M;
            float ps = 0.f, pd = 0.f;
#pragma unroll
            for (int fc = 0; fc < 4; ++fc) {
                float v = acc[fr][fc][q];
                if (ok) Hbuf[(size_t)row * HC + head * 64 + fc * 16 + r16] = v;
                ps = fmaf(v, asv[fc], ps);
                pd = fmaf(v, adv[fc], pd);
            }
#pragma unroll
            for (int off = 8; off >= 1; off >>= 1) {
                ps += __shfl_xor(ps, off);
                pd += __shfl_xor(pd, off);
            }
            if (ok && r16 == 0) {
                a_src[row * NHEAD + head] = ps;
                a_dst[row * NHEAD + head] = pd;
            }
        }
    }
}

// ---------------- CSR build (deg zeroed by hipMemsetAsync) ----------------
__global__ void count_kernel(const int* __restrict__ dst, int* deg, int e) {
    int i = blockIdx.x * blockDim.x + threadIdx.x;
    if (i < e) atomicAdd(&deg[dst[i]], 1);
}
// scan of (deg[i] + 1): self-loop slot folded into the scan
__global__ __launch_bounds__(256) void scan_block_kernel(
    const int* __restrict__ deg, int* __restrict__ excl,
    int* __restrict__ partials, int n)
{
    __shared__ int s[256];
    int t = threadIdx.x;
    int i = blockIdx.x * 256 + t;
    int v = (i < n) ? (deg[i] + 1) : 0;
    s[t] = v;
    __syncthreads();
    int x = v;
#pragma unroll
    for (int off = 1; off < 256; off <<= 1) {
        int y = (t >= off) ? s[t - off] : 0;
        __syncthreads();
        x += y;
        s[t] = x;
        __syncthreads();
    }
    if (i < n) excl[i] = x - v;
    if (t == 255) partials[blockIdx.x] = x;
}
__global__ __launch_bounds__(256) void scan_partials_kernel(int* partials, int nb) {
    __shared__ int s[256];
    int t = threadIdx.x;
    int v = (t < nb) ? partials[t] : 0;
    s[t] = v;
    __syncthreads();
    int x = v;
#pragma unroll
    for (int off = 1; off < 256; off <<= 1) {
        int y = (t >= off) ? s[t - off] : 0;
        __syncthreads();
        x += y;
        s[t] = x;
        __syncthreads();
    }
    if (t < nb) partials[t] = x - v;  // exclusive
}
// fused: offsets + self-loop scatter + self-loop scores + dsum init
__global__ void offs_self_kernel(
    const int* __restrict__ excl, const int* __restrict__ partials,
    const float* __restrict__ a_src, const float* __restrict__ a_dst,
    int* __restrict__ offs, int* __restrict__ esrc, int* __restrict__ cursor,
    float* __restrict__ wexp, float* __restrict__ dsum, int n, int total)
{
    int i = blockIdx.x * blockDim.x + threadIdx.x;
    if (i >= n) return;
    int off = excl[i] + partials[i >> 8];
    offs[i] = off;
    if (i == 0) offs[n] = total;
    esrc[off] = i;
    cursor[i] = off + 1;
    float4 as = *(const float4*)(a_src + (size_t)i * 4);
    float4 ad = *(const float4*)(a_dst + (size_t)i * 4);
    float4 w;
    w.x = leaky_exp(as.x + ad.x);
    w.y = leaky_exp(as.y + ad.y);
    w.z = leaky_exp(as.z + ad.z);
    w.w = leaky_exp(as.w + ad.w);
    *(float4*)(wexp + (size_t)off * 4) = w;
    *(float4*)(dsum + (size_t)i * 4) = w;   // non-atomic init (runs before edges)
}
// fused: edge scatter + per-edge scores for all 4 heads + denominator atomics
__global__ void scatter_edges_kernel(
    const int* __restrict__ src, const int* __restrict__ dst,
    const float* __restrict__ a_src, const float* __restrict__ a_dst,
    int* __restrict__ cursor, int* __restrict__ esrc,
    float* __restrict__ wexp, float* __restrict__ dsum, int e)
{
    int i = blockIdx.x * blockDim.x + threadIdx.x;
    if (i >= e) return;
    int s  = src[i];
    int dt = dst[i];
    int p  = atomicAdd(&cursor[dt], 1);
    esrc[p] = s;
    float4 as = *(const float4*)(a_src + (size_t)s * 4);
    float4 ad = *(const float4*)(a_dst + (size_t)dt * 4);
    float w0 = leaky_exp(as.x + ad.x);
    float w1 = leaky_exp(as.y + ad.y);
    float w2 = leaky_exp(as.z + ad.z);
    float w3 = leaky_exp(as.w + ad.w);
    *(float4*)(wexp + (size_t)p * 4) = make_float4(w0, w1, w2, w3);
    atomicAdd(&dsum[(size_t)dt * 4 + 0], w0);
    atomicAdd(&dsum[(size_t)dt * 4 + 1], w1);
    atomicAdd(&dsum[(size_t)dt * 4 + 2], w2);
    atomicAdd(&dsum[(size_t)dt * 4 + 3], w3);
}

// ---- aggregate: pure gather-FMA (scores/denominators precomputed) ----
// block = node, wave = head, lane = channel. esrc/wexp reads are
// wave-uniform -> scalar loads; 8 gathers in flight.
__global__ __launch_bounds__(256) void aggregate_kernel(
    const float* __restrict__ Hbuf,   // [N,256]
    const int* __restrict__ offs,     // [N+1]
    const int* __restrict__ esrc,     // [E+N]
    const float* __restrict__ wexp,   // [E+N,4]
    const float* __restrict__ dsum,   // [N,4]
    const float* __restrict__ bias,   // [256]
    const float* __restrict__ prelu_a,
    float* __restrict__ out)          // [N,256]
{
    int node = blockIdx.x;
    int head = threadIdx.x >> 6;
    int lane = threadIdx.x & 63;

    int beg = offs[node];
    int end = offs[node + 1];
    float d = dsum[(size_t)node * 4 + head];
    const float* hb = Hbuf + head * CDIM + lane;

    float a0 = 0.f, a1 = 0.f, a2 = 0.f, a3 = 0.f;
    float a4 = 0.f, a5 = 0.f, a6 = 0.f, a7 = 0.f;
    int j = beg;
    for (; j + 8 <= end; j += 8) {
        int s0 = esrc[j + 0], s1 = esrc[j + 1], s2 = esrc[j + 2], s3 = esrc[j + 3];
        int s4 = esrc[j + 4], s5 = esrc[j + 5], s6 = esrc[j + 6], s7 = esrc[j + 7];
        float w0 = wexp[(size_t)(j + 0) * 4 + head];
        float w1 = wexp[(size_t)(j + 1) * 4 + head];
        float w2 = wexp[(size_t)(j + 2) * 4 + head];
        float w3 = wexp[(size_t)(j + 3) * 4 + head];
        float w4 = wexp[(size_t)(j + 4) * 4 + head];
        float w5 = wexp[(size_t)(j + 5) * 4 + head];
        float w6 = wexp[(size_t)(j + 6) * 4 + head];
        float w7 = wexp[(size_t)(j + 7) * 4 + head];
        a0 = fmaf(w0, hb[(size_t)s0 * HC], a0);
        a1 = fmaf(w1, hb[(size_t)s1 * HC], a1);
        a2 = fmaf(w2, hb[(size_t)s2 * HC], a2);
        a3 = fmaf(w3, hb[(size_t)s3 * HC], a3);
        a4 = fmaf(w4, hb[(size_t)s4 * HC], a4);
        a5 = fmaf(w5, hb[(size_t)s5 * HC], a5);
        a6 = fmaf(w6, hb[(size_t)s6 * HC], a6);
        a7 = fmaf(w7, hb[(size_t)s7 * HC], a7);
    }
    for (; j < end; ++j) {
        int s0 = esrc[j];
        float w0 = wexp[(size_t)j * 4 + head];
        a0 = fmaf(w0, hb[(size_t)s0 * HC], a0);
    }
    float acc = ((a0 + a1) + (a2 + a3)) + ((a4 + a5) + (a6 + a7));
    float o = acc / (d + 1e-16f) + bias[head * CDIM + lane];
    float pa = prelu_a[0];
    out[(size_t)node * HC + head * CDIM + lane] = (o >= 0.f) ? o : pa * o;
}

// ---------------- launcher ----------------
static inline size_t align256(size_t x) { return (x + 255) & ~(size_t)255; }

extern "C" void kernel_launch(void* const* d_in, const int* in_sizes, int n_in,
                              void* d_out, int out_size, void* d_ws, size_t ws_size,
                              hipStream_t stream) {
    const float* x       = (const float*)d_in[0];
    const int*   eidx    = (const int*)d_in[1];
    const float* W       = (const float*)d_in[2];
    const float* att_src = (const float*)d_in[3];
    const float* att_dst = (const float*)d_in[4];
    const float* bias    = (const float*)d_in[5];
    const float* prelu_a = (const float*)d_in[6];
    float* out = (float*)d_out;

    const int N = in_sizes[0] / IN_DIM;      // 50000
    const int E = in_sizes[1] / 2;           // 500000
    const int* esrc_in = eidx;
    const int* edst_in = eidx + E;

    char* w = (char*)d_ws;
    unsigned short* Wp_hi = (unsigned short*)w; w += align256((size_t)IN_DIM * HC * 2);
    unsigned short* Wp_lo = (unsigned short*)w; w += align256((size_t)IN_DIM * HC * 2);
    float* Hbuf   = (float*)w; w += align256((size_t)N * HC * 4);
    float* a_srcB = (float*)w; w += align256((size_t)N * NHEAD * 4);
    float* a_dstB = (float*)w; w += align256((size_t)N * NHEAD * 4);
    int*   deg    = (int*)w;   w += align256((size_t)N * 4);
    int*   excl   = (int*)w;   w += align256((size_t)N * 4);
    int*   parts  = (int*)w;   w += align256(256 * 4);
    int*   offs   = (int*)w;   w += align256((size_t)(N + 1) * 4);
    int*   cursor = (int*)w;   w += align256((size_t)N * 4);
    int*   esrc   = (int*)w;   w += align256((size_t)(E + N) * 4);
    float* wexp   = (float*)w; w += align256((size_t)(E + N) * 4 * 4);
    float* dsum   = (float*)w; w += align256((size_t)N * 4 * 4);

    hipMemsetAsync(deg, 0, (size_t)N * 4, stream);
    prep_w_kernel<<<64, 256, 0, stream>>>(W, Wp_hi, Wp_lo);
    gemm_coef_kernel<<<(N + GBM - 1) / GBM, 512, 0, stream>>>(
        x, Wp_hi, Wp_lo, att_src, att_dst, Hbuf, a_srcB, a_dstB, N);

    {
        int nb = (N + 255) / 256;
        int eb = (E + 255) / 256;
        count_kernel<<<eb, 256, 0, stream>>>(edst_in, deg, E);
        scan_block_kernel<<<nb, 256, 0, stream>>>(deg, excl, parts, N);
        scan_partials_kernel<<<1, 256, 0, stream>>>(parts, nb);
        offs_self_kernel<<<nb, 256, 0, stream>>>(excl, parts, a_srcB, a_dstB,
                                                 offs, esrc, cursor, wexp, dsum, N, E + N);
        scatter_edges_kernel<<<eb, 256, 0, stream>>>(esrc_in, edst_in, a_srcB, a_dstB,
                                                     cursor, esrc, wexp, dsum, E);
    }

    aggregate_kernel<<<N, 256, 0, stream>>>(Hbuf, offs, esrc, wexp, dsum,
                                            bias, prelu_a, out);
}

// Round 6
// 360.874 us; speedup vs baseline: 1.2714x; 1.2714x over previous
//
#include <hip/hip_runtime.h>
#include <hip/hip_bf16.h>
#include <math.h>

#define IN_DIM 512
#define NHEAD 4
#define CDIM 64
#define HC 256           // NHEAD*CDIM
#define NEG_SLOPE 0.2f
#define GBM 128          // GEMM rows per block

typedef __attribute__((ext_vector_type(8))) short bf16x8;
typedef __attribute__((ext_vector_type(4))) float f32x4;

__device__ __forceinline__ unsigned short f2bf_rne(float f) {
    unsigned int u = __float_as_uint(f);
    u = u + 0x7fffu + ((u >> 16) & 1u);
    return (unsigned short)(u >> 16);
}
__device__ __forceinline__ float bf2f(unsigned short h) {
    return __uint_as_float(((unsigned int)h) << 16);
}
__device__ __forceinline__ float leaky_exp(float t) {
    t = (t >= 0.f) ? t : NEG_SLOPE * t;
    return __expf(t);
}

// ---- W prep: split fp32 W[512][256] into bf16 hi/lo panels, transposed +
// bank-swizzle pre-permuted so the GEMM stages B with linear global_load_lds.
__global__ __launch_bounds__(256) void prep_w_kernel(
    const float* __restrict__ W,
    unsigned short* __restrict__ Wp_hi,
    unsigned short* __restrict__ Wp_lo)
{
    int idx = blockIdx.x * 256 + threadIdx.x;   // 16 ksteps * 256 cols * 4 slots
    int slot  = idx & 3;
    int col   = (idx >> 2) & 255;
    int kstep = idx >> 10;
    int kg    = slot ^ ((col >> 1) & 3);
    int kbase = kstep * 32 + kg * 8;
    bf16x8 vh, vl;
#pragma unroll
    for (int e = 0; e < 8; ++e) {
        float f = W[(size_t)(kbase + e) * HC + col];
        unsigned short h = f2bf_rne(f);
        vh[e] = (short)h;
        vl[e] = (short)f2bf_rne(f - bf2f(h));
    }
    size_t off = (size_t)idx * 8;
    *(bf16x8*)(Wp_hi + off) = vh;
    *(bf16x8*)(Wp_lo + off) = vl;
}

// ---- GEMM h = x@W via bf16 split MFMA, pipelined (B double-buffered,
// A reg-prefetch), fused attention-coef epilogue. 512 thr = 8 waves
// (2 row x 4 col groups); col group == head.
__global__ __launch_bounds__(512) void gemm_coef_kernel(
    const float* __restrict__ x,
    const unsigned short* __restrict__ Wp_hi,
    const unsigned short* __restrict__ Wp_lo,
    const float* __restrict__ att_src,
    const float* __restrict__ att_dst,
    float* __restrict__ Hbuf,
    float* __restrict__ a_src,
    float* __restrict__ a_dst,
    int M)
{
    __shared__ char smem[81920];
    char* As_hi = smem;                 // 128 rows * 64B = 8KB
    char* As_lo = smem + 8192;          // 8KB
    // B double buffer at smem+16384: buf b = +b*32768 (hi 16KB, lo 16KB)

    const int tid  = threadIdx.x;
    const int lane = tid & 63;
    const int wv   = tid >> 6;         // 0..7
    const int head = wv & 3;
    const int wrow = (wv >> 2) * 64;
    const int brow = blockIdx.x * GBM;
    const int r16  = lane & 15;
    const int kgrp = lane >> 4;

    const int  ar      = tid >> 2;     // 0..127 (row within tile)
    const int  aslot   = tid & 3;      // 16B slot within row
    const bool arow_ok = (brow + ar) < M;
    const float* aptr  = x + (size_t)(brow + ar) * IN_DIM + aslot * 8;
    const int  a_addr  = ar * 64 + ((aslot ^ ((ar >> 1) & 3)) << 4);

    f32x4 acc[4][4];
#pragma unroll
    for (int i = 0; i < 4; ++i)
#pragma unroll
        for (int j = 0; j < 4; ++j) acc[i][j] = (f32x4)(0.f);

    auto stageB = [&](int ks, int buf) {
        const char* gh = (const char*)Wp_hi + (size_t)ks * 16384 + wv * 2048 + (lane << 4);
        const char* gl = (const char*)Wp_lo + (size_t)ks * 16384 + wv * 2048 + (lane << 4);
        char* lh = smem + 16384 + buf * 32768 + wv * 2048;
        char* ll = lh + 16384;
#pragma unroll
        for (int i = 0; i < 2; ++i) {
            __builtin_amdgcn_global_load_lds(
                (const __attribute__((address_space(1))) unsigned int*)(gh + i * 1024),
                (__attribute__((address_space(3))) unsigned int*)(lh + i * 1024), 16, 0, 0);
            __builtin_amdgcn_global_load_lds(
                (const __attribute__((address_space(1))) unsigned int*)(gl + i * 1024),
                (__attribute__((address_space(3))) unsigned int*)(ll + i * 1024), 16, 0, 0);
        }
    };
    auto loadA = [&](int ks, float4& v0, float4& v1) {
        v0 = make_float4(0.f, 0.f, 0.f, 0.f);
        v1 = v0;
        if (arow_ok) {
            const float* p = aptr + ks * 32;
            v0 = *(const float4*)p;
            v1 = *(const float4*)(p + 4);
        }
    };
    auto writeA = [&](const float4& v0, const float4& v1) {
        float fv[8] = {v0.x, v0.y, v0.z, v0.w, v1.x, v1.y, v1.z, v1.w};
        bf16x8 vh, vl;
#pragma unroll
        for (int e = 0; e < 8; ++e) {
            unsigned short hh = f2bf_rne(fv[e]);
            vh[e] = (short)hh;
            vl[e] = (short)f2bf_rne(fv[e] - bf2f(hh));
        }
        *(bf16x8*)(As_hi + a_addr) = vh;
        *(bf16x8*)(As_lo + a_addr) = vl;
    };

    // prologue
    {
        float4 pv0, pv1;
        stageB(0, 0);
        loadA(0, pv0, pv1);
        writeA(pv0, pv1);
        __syncthreads();   // drains vmcnt (B0 in LDS) + lgkm (A0 in LDS)
    }

    for (int ks = 0; ks < 16; ++ks) {
        const int cb = ks & 1;
        float4 nv0, nv1;
        if (ks < 15) {
            stageB(ks + 1, cb ^ 1);   // async into other B buffer
            loadA(ks + 1, nv0, nv1);  // A prefetch to regs
        }

        bf16x8 ah[4], al[4], bh[4], bl[4];
        char* BsH = smem + 16384 + cb * 32768;
        char* BsL = BsH + 16384;
#pragma unroll
        for (int fr = 0; fr < 4; ++fr) {
            int row = wrow + fr * 16 + r16;
            int addr = row * 64 + ((kgrp ^ ((row >> 1) & 3)) << 4);
            ah[fr] = *(bf16x8*)(As_hi + addr);
            al[fr] = *(bf16x8*)(As_lo + addr);
        }
#pragma unroll
        for (int fc = 0; fc < 4; ++fc) {
            int col = head * 64 + fc * 16 + r16;
            int addr = col * 64 + ((kgrp ^ ((col >> 1) & 3)) << 4);
            bh[fc] = *(bf16x8*)(BsH + addr);
            bl[fc] = *(bf16x8*)(BsL + addr);
        }
#pragma unroll
        for (int fr = 0; fr < 4; ++fr)
#pragma unroll
            for (int fc = 0; fc < 4; ++fc) {
                acc[fr][fc] = __builtin_amdgcn_mfma_f32_16x16x32_bf16(ah[fr], bh[fc], acc[fr][fc], 0, 0, 0);
                acc[fr][fc] = __builtin_amdgcn_mfma_f32_16x16x32_bf16(ah[fr], bl[fc], acc[fr][fc], 0, 0, 0);
                acc[fr][fc] = __builtin_amdgcn_mfma_f32_16x16x32_bf16(al[fr], bh[fc], acc[fr][fc], 0, 0, 0);
            }

        if (ks < 15) {
            __syncthreads();     // all ds_reads of As done -> safe to overwrite
            writeA(nv0, nv1);
            __syncthreads();     // As(next) visible; drains vmcnt -> Bs(next) ready
        }
    }

    // epilogue: store Hbuf + fused a_src/a_dst (wave col-group == head)
    float asv[4], adv[4];
#pragma unroll
    for (int fc = 0; fc < 4; ++fc) {
        int col = head * 64 + fc * 16 + r16;
        asv[fc] = att_src[col];
        adv[fc] = att_dst[col];
    }
#pragma unroll
    for (int fr = 0; fr < 4; ++fr) {
#pragma unroll
        for (int q = 0; q < 4; ++q) {
            int row = brow + wrow + fr * 16 + kgrp * 4 + q;
            bool ok = row < M;
            float ps = 0.f, pd = 0.f;
#pragma unroll
            for (int fc = 0; fc < 4; ++fc) {
                float v = acc[fr][fc][q];
                if (ok) Hbuf[(size_t)row * HC + head * 64 + fc * 16 + r16] = v;
                ps = fmaf(v, asv[fc], ps);
                pd = fmaf(v, adv[fc], pd);
            }
#pragma unroll
            for (int off = 8; off >= 1; off >>= 1) {
                ps += __shfl_xor(ps, off);
                pd += __shfl_xor(pd, off);
            }
            if (ok && r16 == 0) {
                a_src[row * NHEAD + head] = ps;
                a_dst[row * NHEAD + head] = pd;
            }
        }
    }
}

// ---------------- CSR build (deg zeroed by hipMemsetAsync) ----------------
__global__ void count_kernel(const int* __restrict__ dst, int* deg, int e) {
    int i = blockIdx.x * blockDim.x + threadIdx.x;
    if (i < e) atomicAdd(&deg[dst[i]], 1);
}
// scan of (deg[i] + 1): self-loop slot folded into the scan
__global__ __launch_bounds__(256) void scan_block_kernel(
    const int* __restrict__ deg, int* __restrict__ excl,
    int* __restrict__ partials, int n)
{
    __shared__ int s[256];
    int t = threadIdx.x;
    int i = blockIdx.x * 256 + t;
    int v = (i < n) ? (deg[i] + 1) : 0;
    s[t] = v;
    __syncthreads();
    int x = v;
#pragma unroll
    for (int off = 1; off < 256; off <<= 1) {
        int y = (t >= off) ? s[t - off] : 0;
        __syncthreads();
        x += y;
        s[t] = x;
        __syncthreads();
    }
    if (i < n) excl[i] = x - v;
    if (t == 255) partials[blockIdx.x] = x;
}
__global__ __launch_bounds__(256) void scan_partials_kernel(int* partials, int nb) {
    __shared__ int s[256];
    int t = threadIdx.x;
    int v = (t < nb) ? partials[t] : 0;
    s[t] = v;
    __syncthreads();
    int x = v;
#pragma unroll
    for (int off = 1; off < 256; off <<= 1) {
        int y = (t >= off) ? s[t - off] : 0;
        __syncthreads();
        x += y;
        s[t] = x;
        __syncthreads();
    }
    if (t < nb) partials[t] = x - v;  // exclusive
}
// fused: offsets + self-loop scatter + self-loop scores
__global__ void offs_self_kernel(
    const int* __restrict__ excl, const int* __restrict__ partials,
    const float* __restrict__ a_src, const float* __restrict__ a_dst,
    int* __restrict__ offs, int* __restrict__ esrc, int* __restrict__ cursor,
    float* __restrict__ wexp, int n, int total)
{
    int i = blockIdx.x * blockDim.x + threadIdx.x;
    if (i >= n) return;
    int off = excl[i] + partials[i >> 8];
    offs[i] = off;
    if (i == 0) offs[n] = total;
    esrc[off] = i;
    cursor[i] = off + 1;
    float4 as = *(const float4*)(a_src + (size_t)i * 4);
    float4 ad = *(const float4*)(a_dst + (size_t)i * 4);
    float4 w;
    w.x = leaky_exp(as.x + ad.x);
    w.y = leaky_exp(as.y + ad.y);
    w.z = leaky_exp(as.z + ad.z);
    w.w = leaky_exp(as.w + ad.w);
    *(float4*)(wexp + (size_t)off * 4) = w;
}
// fused: edge scatter + per-edge scores for all 4 heads (NO float atomics)
__global__ void scatter_edges_kernel(
    const int* __restrict__ src, const int* __restrict__ dst,
    const float* __restrict__ a_src, const float* __restrict__ a_dst,
    int* __restrict__ cursor, int* __restrict__ esrc,
    float* __restrict__ wexp, int e)
{
    int i = blockIdx.x * blockDim.x + threadIdx.x;
    if (i >= e) return;
    int s  = src[i];
    int dt = dst[i];
    int p  = atomicAdd(&cursor[dt], 1);
    esrc[p] = s;
    float4 as = *(const float4*)(a_src + (size_t)s * 4);
    float4 ad = *(const float4*)(a_dst + (size_t)dt * 4);
    float4 w;
    w.x = leaky_exp(as.x + ad.x);
    w.y = leaky_exp(as.y + ad.y);
    w.z = leaky_exp(as.z + ad.z);
    w.w = leaky_exp(as.w + ad.w);
    *(float4*)(wexp + (size_t)p * 4) = w;
}

// ---- aggregate: gather-FMA with float4 lanes (4 edges/wave concurrent),
// denominator accumulated inline from wexp (no atomics, no extra traffic).
// block = node, wave = head; lane = (edge_slot e16 = lane>>4, chan-quad c4).
__global__ __launch_bounds__(256) void aggregate_kernel(
    const float* __restrict__ Hbuf,   // [N,256]
    const int* __restrict__ offs,     // [N+1]
    const int* __restrict__ esrc,     // [E+N]
    const float* __restrict__ wexp,   // [E+N,4]
    const float* __restrict__ bias,   // [256]
    const float* __restrict__ prelu_a,
    float* __restrict__ out)          // [N,256]
{
    int node = blockIdx.x;
    int head = threadIdx.x >> 6;
    int lane = threadIdx.x & 63;
    int e16  = lane >> 4;     // edge slot 0..3
    int c4   = lane & 15;     // channel quad 0..15

    int beg = offs[node];
    int end = offs[node + 1];
    const float* hb = Hbuf + head * CDIM + c4 * 4;

    float4 acc0 = make_float4(0.f, 0.f, 0.f, 0.f);
    float4 acc1 = acc0, acc2 = acc0, acc3 = acc0;
    float d0 = 0.f, d1 = 0.f, d2 = 0.f, d3 = 0.f;

    for (int j = beg + e16; j < end; j += 16) {
        // u=0
        {
            int s = esrc[j];
            float w = wexp[(size_t)j * 4 + head];
            float4 v = *(const float4*)(hb + (size_t)s * HC);
            acc0.x = fmaf(w, v.x, acc0.x); acc0.y = fmaf(w, v.y, acc0.y);
            acc0.z = fmaf(w, v.z, acc0.z); acc0.w = fmaf(w, v.w, acc0.w);
            d0 += w;
        }
        int j1 = j + 4, j2 = j + 8, j3 = j + 12;
        if (j1 < end) {
            int s = esrc[j1];
            float w = wexp[(size_t)j1 * 4 + head];
            float4 v = *(const float4*)(hb + (size_t)s * HC);
            acc1.x = fmaf(w, v.x, acc1.x); acc1.y = fmaf(w, v.y, acc1.y);
            acc1.z = fmaf(w, v.z, acc1.z); acc1.w = fmaf(w, v.w, acc1.w);
            d1 += w;
        }
        if (j2 < end) {
            int s = esrc[j2];
            float w = wexp[(size_t)j2 * 4 + head];
            float4 v = *(const float4*)(hb + (size_t)s * HC);
            acc2.x = fmaf(w, v.x, acc2.x); acc2.y = fmaf(w, v.y, acc2.y);
            acc2.z = fmaf(w, v.z, acc2.z); acc2.w = fmaf(w, v.w, acc2.w);
            d2 += w;
        }
        if (j3 < end) {
            int s = esrc[j3];
            float w = wexp[(size_t)j3 * 4 + head];
            float4 v = *(const float4*)(hb + (size_t)s * HC);
            acc3.x = fmaf(w, v.x, acc3.x); acc3.y = fmaf(w, v.y, acc3.y);
            acc3.z = fmaf(w, v.z, acc3.z); acc3.w = fmaf(w, v.w, acc3.w);
            d3 += w;
        }
    }
    float4 acc = make_float4((acc0.x + acc1.x) + (acc2.x + acc3.x),
                             (acc0.y + acc1.y) + (acc2.y + acc3.y),
                             (acc0.z + acc1.z) + (acc2.z + acc3.z),
                             (acc0.w + acc1.w) + (acc2.w + acc3.w));
    float d = (d0 + d1) + (d2 + d3);
    // reduce across the 4 edge-slot groups (xor 16, 32)
#pragma unroll
    for (int off = 16; off <= 32; off <<= 1) {
        acc.x += __shfl_xor(acc.x, off);
        acc.y += __shfl_xor(acc.y, off);
        acc.z += __shfl_xor(acc.z, off);
        acc.w += __shfl_xor(acc.w, off);
        d     += __shfl_xor(d, off);
    }
    if (e16 == 0) {
        float inv = 1.f / (d + 1e-16f);
        float4 b = *(const float4*)(bias + head * CDIM + c4 * 4);
        float pa = prelu_a[0];
        float4 o;
        o.x = acc.x * inv + b.x;
        o.y = acc.y * inv + b.y;
        o.z = acc.z * inv + b.z;
        o.w = acc.w * inv + b.w;
        o.x = (o.x >= 0.f) ? o.x : pa * o.x;
        o.y = (o.y >= 0.f) ? o.y : pa * o.y;
        o.z = (o.z >= 0.f) ? o.z : pa * o.z;
        o.w = (o.w >= 0.f) ? o.w : pa * o.w;
        *(float4*)(out + (size_t)node * HC + head * CDIM + c4 * 4) = o;
    }
}

// ---------------- launcher ----------------
static inline size_t align256(size_t x) { return (x + 255) & ~(size_t)255; }

extern "C" void kernel_launch(void* const* d_in, const int* in_sizes, int n_in,
                              void* d_out, int out_size, void* d_ws, size_t ws_size,
                              hipStream_t stream) {
    const float* x       = (const float*)d_in[0];
    const int*   eidx    = (const int*)d_in[1];
    const float* W       = (const float*)d_in[2];
    const float* att_src = (const float*)d_in[3];
    const float* att_dst = (const float*)d_in[4];
    const float* bias    = (const float*)d_in[5];
    const float* prelu_a = (const float*)d_in[6];
    float* out = (float*)d_out;

    const int N = in_sizes[0] / IN_DIM;      // 50000
    const int E = in_sizes[1] / 2;           // 500000
    const int* esrc_in = eidx;
    const int* edst_in = eidx + E;

    char* w = (char*)d_ws;
    unsigned short* Wp_hi = (unsigned short*)w; w += align256((size_t)IN_DIM * HC * 2);
    unsigned short* Wp_lo = (unsigned short*)w; w += align256((size_t)IN_DIM * HC * 2);
    float* Hbuf   = (float*)w; w += align256((size_t)N * HC * 4);
    float* a_srcB = (float*)w; w += align256((size_t)N * NHEAD * 4);
    float* a_dstB = (float*)w; w += align256((size_t)N * NHEAD * 4);
    int*   deg    = (int*)w;   w += align256((size_t)N * 4);
    int*   excl   = (int*)w;   w += align256((size_t)N * 4);
    int*   parts  = (int*)w;   w += align256(256 * 4);
    int*   offs   = (int*)w;   w += align256((size_t)(N + 1) * 4);
    int*   cursor = (int*)w;   w += align256((size_t)N * 4);
    int*   esrc   = (int*)w;   w += align256((size_t)(E + N) * 4);
    float* wexp   = (float*)w; w += align256((size_t)(E + N) * 4 * 4);

    hipMemsetAsync(deg, 0, (size_t)N * 4, stream);
    prep_w_kernel<<<64, 256, 0, stream>>>(W, Wp_hi, Wp_lo);
    gemm_coef_kernel<<<(N + GBM - 1) / GBM, 512, 0, stream>>>(
        x, Wp_hi, Wp_lo, att_src, att_dst, Hbuf, a_srcB, a_dstB, N);

    {
        int nb = (N + 255) / 256;
        int eb = (E + 255) / 256;
        count_kernel<<<eb, 256, 0, stream>>>(edst_in, deg, E);
        scan_block_kernel<<<nb, 256, 0, stream>>>(deg, excl, parts, N);
        scan_partials_kernel<<<1, 256, 0, stream>>>(parts, nb);
        offs_self_kernel<<<nb, 256, 0, stream>>>(excl, parts, a_srcB, a_dstB,
                                                 offs, esrc, cursor, wexp, N, E + N);
        scatter_edges_kernel<<<eb, 256, 0, stream>>>(esrc_in, edst_in, a_srcB, a_dstB,
                                                     cursor, esrc, wexp, E);
    }

    aggregate_kernel<<<N, 256, 0, stream>>>(Hbuf, offs, esrc, wexp,
                                            bias, prelu_a, out);
}